// Round 1
// baseline (1352.006 us; speedup 1.0000x reference)
//
#include <hip/hip_runtime.h>
#include <hip/hip_bf16.h>

// Problem: CausalSelfAttention  B=1, T=4096, C=768, H=12, hd=64
// Round 0: correctness-first fp32 implementation.
//   kernel 1: qkv = x @ w_qkv + b_qkv          [4096,2304]
//   kernel 2: flash-style causal attention     [4096,768]
//   kernel 3: out = attn @ w_proj + b_proj     [4096,768]

#define T_SEQ 4096
#define C_DIM 768
#define C3    2304
#define NH    12
#define HD    64

// ---------------------------------------------------------------------------
// Generic tiled fp32 GEMM: C[M,N] = A[M,K] @ B[K,N] + bias[N]
// 64x64 tile, BK=16, 256 threads, 4x4 microtile (strided by 16).
// ---------------------------------------------------------------------------
__global__ __launch_bounds__(256) void gemm_bias_f32(
    const float* __restrict__ A, const float* __restrict__ B,
    const float* __restrict__ bias, float* __restrict__ C,
    int M, int N, int K) {
  __shared__ float As[16][65];  // As[k][m], padded
  __shared__ float Bs[16][65];  // Bs[k][n], padded
  const int tid = threadIdx.x;
  const int tx = tid & 15, ty = tid >> 4;
  const int bm = blockIdx.y * 64, bn = blockIdx.x * 64;

  float c[4][4] = {};

  for (int k0 = 0; k0 < K; k0 += 16) {
    // load A tile 64 rows x 16 k  (1024 elems / 256 thr = 4 each)
#pragma unroll
    for (int l = 0; l < 4; ++l) {
      int e = tid + 256 * l;
      int m = e >> 4, kk = e & 15;
      As[kk][m] = A[(size_t)(bm + m) * K + k0 + kk];
    }
    // load B tile 16 k x 64 n
#pragma unroll
    for (int l = 0; l < 4; ++l) {
      int e = tid + 256 * l;
      int kk = e >> 6, n = e & 63;
      Bs[kk][n] = B[(size_t)(k0 + kk) * N + bn + n];
    }
    __syncthreads();
#pragma unroll
    for (int kk = 0; kk < 16; ++kk) {
      float a[4], b[4];
#pragma unroll
      for (int i = 0; i < 4; ++i) a[i] = As[kk][i * 16 + ty];
#pragma unroll
      for (int j = 0; j < 4; ++j) b[j] = Bs[kk][j * 16 + tx];
#pragma unroll
      for (int i = 0; i < 4; ++i)
#pragma unroll
        for (int j = 0; j < 4; ++j) c[i][j] += a[i] * b[j];
    }
    __syncthreads();
  }

#pragma unroll
  for (int i = 0; i < 4; ++i)
#pragma unroll
    for (int j = 0; j < 4; ++j) {
      int m = bm + i * 16 + ty, n = bn + j * 16 + tx;
      C[(size_t)m * N + n] = c[i][j] + bias[n];
    }
}

// ---------------------------------------------------------------------------
// Flash-style causal attention, fp32.
// grid = (T/64, H), block = 256. One 64-row Q tile per block.
// qkv layout: [T, 3C]; Q at col h*64, K at 768+h*64, V at 1536+h*64.
// out layout: [T, C] with head h at cols h*64..h*64+63.
// ---------------------------------------------------------------------------
__global__ __launch_bounds__(256) void flash_attn_f32(
    const float* __restrict__ qkv, float* __restrict__ out) {
  __shared__ float Qs[64][65];   // padded: reads stride-65 across ty
  __shared__ float KP[64][65];   // union: K tile during S, then P tile
  __shared__ float Vs[64][64];   // reads are stride-1 across tx

  const int h = blockIdx.y;
  const int qt = blockIdx.x;
  const int q0 = qt * 64;
  const int tid = threadIdx.x;
  const int tx = tid & 15, ty = tid >> 4;
  const float scale = 0.125f;  // 1/sqrt(64)

  // load Q tile (64x64), coalesced
#pragma unroll
  for (int l = 0; l < 16; ++l) {
    int e = tid + 256 * l;
    int r = e >> 6, d = e & 63;
    Qs[r][d] = qkv[(size_t)(q0 + r) * C3 + h * HD + d];
  }

  float m_i[4], l_i[4], o[4][4] = {};
#pragma unroll
  for (int i = 0; i < 4; ++i) { m_i[i] = -1e30f; l_i[i] = 0.f; }

  for (int kt = 0; kt <= qt; ++kt) {
    const int k0 = kt * 64;
    __syncthreads();  // protect KP/Vs from previous iteration's readers
    // load K and V tiles
#pragma unroll
    for (int l = 0; l < 16; ++l) {
      int e = tid + 256 * l;
      int r = e >> 6, d = e & 63;
      KP[r][d] = qkv[(size_t)(k0 + r) * C3 + C_DIM + h * HD + d];
      Vs[r][d] = qkv[(size_t)(k0 + r) * C3 + 2 * C_DIM + h * HD + d];
    }
    __syncthreads();

    // S = Q @ K^T  (thread owns rows i*16+ty, cols j*16+tx)
    float s[4][4] = {};
#pragma unroll 8
    for (int d = 0; d < 64; ++d) {
      float a[4], b[4];
#pragma unroll
      for (int i = 0; i < 4; ++i) a[i] = Qs[i * 16 + ty][d];
#pragma unroll
      for (int j = 0; j < 4; ++j) b[j] = KP[j * 16 + tx][d];
#pragma unroll
      for (int i = 0; i < 4; ++i)
#pragma unroll
        for (int j = 0; j < 4; ++j) s[i][j] += a[i] * b[j];
    }

    const bool diag = (kt == qt);
#pragma unroll
    for (int i = 0; i < 4; ++i) {
      const int lrow = i * 16 + ty;
      float mx = -1e30f;
#pragma unroll
      for (int j = 0; j < 4; ++j) {
        s[i][j] *= scale;
        if (diag && (j * 16 + tx > lrow)) s[i][j] = -1e30f;
        mx = fmaxf(mx, s[i][j]);
      }
      // row-max across the 16 lanes (tx) that share this row
#pragma unroll
      for (int off = 1; off < 16; off <<= 1)
        mx = fmaxf(mx, __shfl_xor(mx, off, 16));
      const float mtot = fmaxf(m_i[i], mx);
      const float alpha = __expf(m_i[i] - mtot);
      m_i[i] = mtot;
      float lsum = 0.f;
#pragma unroll
      for (int j = 0; j < 4; ++j) {
        float p = __expf(s[i][j] - mtot);
        s[i][j] = p;
        lsum += p;
      }
#pragma unroll
      for (int off = 1; off < 16; off <<= 1)
        lsum += __shfl_xor(lsum, off, 16);
      l_i[i] = l_i[i] * alpha + lsum;
#pragma unroll
      for (int j = 0; j < 4; ++j) o[i][j] *= alpha;
    }

    __syncthreads();  // all done reading K before overwriting with P
#pragma unroll
    for (int i = 0; i < 4; ++i)
#pragma unroll
      for (int j = 0; j < 4; ++j) KP[i * 16 + ty][j * 16 + tx] = s[i][j];
    __syncthreads();

    // O += P @ V
#pragma unroll 8
    for (int jj = 0; jj < 64; ++jj) {
      float a[4], b[4];
#pragma unroll
      for (int i = 0; i < 4; ++i) a[i] = KP[i * 16 + ty][jj];
#pragma unroll
      for (int j = 0; j < 4; ++j) b[j] = Vs[jj][j * 16 + tx];
#pragma unroll
      for (int i = 0; i < 4; ++i)
#pragma unroll
        for (int j = 0; j < 4; ++j) o[i][j] += a[i] * b[j];
    }
  }

  // write O / l
#pragma unroll
  for (int i = 0; i < 4; ++i) {
    const float inv = 1.0f / l_i[i];
#pragma unroll
    for (int j = 0; j < 4; ++j) {
      int r = q0 + i * 16 + ty, d = j * 16 + tx;
      out[(size_t)r * C_DIM + h * HD + d] = o[i][j] * inv;
    }
  }
}

// ---------------------------------------------------------------------------
extern "C" void kernel_launch(void* const* d_in, const int* in_sizes, int n_in,
                              void* d_out, int out_size, void* d_ws, size_t ws_size,
                              hipStream_t stream) {
  const float* x      = (const float*)d_in[0];  // [4096, 768]
  const float* w_qkv  = (const float*)d_in[1];  // [768, 2304]
  const float* b_qkv  = (const float*)d_in[2];  // [2304]
  const float* w_proj = (const float*)d_in[3];  // [768, 768]
  const float* b_proj = (const float*)d_in[4];  // [768]
  float* out = (float*)d_out;                   // [4096, 768]

  float* qkv  = (float*)d_ws;                         // [4096, 2304] = 37.7 MB
  float* attn = qkv + (size_t)T_SEQ * C3;             // [4096, 768]  = 12.6 MB

  // qkv = x @ w_qkv + b_qkv
  gemm_bias_f32<<<dim3(C3 / 64, T_SEQ / 64), 256, 0, stream>>>(
      x, w_qkv, b_qkv, qkv, T_SEQ, C3, C_DIM);

  // causal flash attention
  flash_attn_f32<<<dim3(T_SEQ / 64, NH), 256, 0, stream>>>(qkv, attn);

  // out = attn @ w_proj + b_proj
  gemm_bias_f32<<<dim3(C_DIM / 64, T_SEQ / 64), 256, 0, stream>>>(
      attn, w_proj, b_proj, out, T_SEQ, C_DIM, C_DIM);
}

// Round 2
// 640.405 us; speedup vs baseline: 2.1112x; 2.1112x over previous
//
#include <hip/hip_runtime.h>
#include <hip/hip_bf16.h>

// CausalSelfAttention  B=1, T=4096, C=768, H=12, hd=64
// Round 2: MFMA bf16 flash attention; fp32 GEMMs (gemm1 emits bf16 qkv).

#define T_SEQ 4096
#define C_DIM 768
#define C3    2304
#define NH    12
#define HD    64

typedef __attribute__((ext_vector_type(8))) short bf16x8;
typedef __attribute__((ext_vector_type(4))) float f32x4;

__device__ inline unsigned short f2bf(float f) {
  union { float f; unsigned u; } v; v.f = f;
  unsigned r = v.u + 0x7fff + ((v.u >> 16) & 1);  // RTNE
  return (unsigned short)(r >> 16);
}

__device__ inline void store_out(float v, float* p) { *p = v; }
__device__ inline void store_out(float v, unsigned short* p) { *p = f2bf(v); }

// ---------------------------------------------------------------------------
// fp32 tiled GEMM: C[M,N] = A[M,K] @ B[K,N] + bias[N]; OutT = float or bf16.
// ---------------------------------------------------------------------------
template <typename OutT>
__global__ __launch_bounds__(256) void gemm_bias_f32_k(
    const float* __restrict__ A, const float* __restrict__ B,
    const float* __restrict__ bias, OutT* __restrict__ C,
    int M, int N, int K) {
  __shared__ float As[16][65];
  __shared__ float Bs[16][65];
  const int tid = threadIdx.x;
  const int tx = tid & 15, ty = tid >> 4;
  const int bm = blockIdx.y * 64, bn = blockIdx.x * 64;

  float c[4][4] = {};

  for (int k0 = 0; k0 < K; k0 += 16) {
#pragma unroll
    for (int l = 0; l < 4; ++l) {
      int e = tid + 256 * l;
      int m = e >> 4, kk = e & 15;
      As[kk][m] = A[(size_t)(bm + m) * K + k0 + kk];
    }
#pragma unroll
    for (int l = 0; l < 4; ++l) {
      int e = tid + 256 * l;
      int kk = e >> 6, n = e & 63;
      Bs[kk][n] = B[(size_t)(k0 + kk) * N + bn + n];
    }
    __syncthreads();
#pragma unroll
    for (int kk = 0; kk < 16; ++kk) {
      float a[4], b[4];
#pragma unroll
      for (int i = 0; i < 4; ++i) a[i] = As[kk][i * 16 + ty];
#pragma unroll
      for (int j = 0; j < 4; ++j) b[j] = Bs[kk][j * 16 + tx];
#pragma unroll
      for (int i = 0; i < 4; ++i)
#pragma unroll
        for (int j = 0; j < 4; ++j) c[i][j] += a[i] * b[j];
    }
    __syncthreads();
  }

#pragma unroll
  for (int i = 0; i < 4; ++i)
#pragma unroll
    for (int j = 0; j < 4; ++j) {
      int m = bm + i * 16 + ty, n = bn + j * 16 + tx;
      store_out(c[i][j] + bias[n], &C[(size_t)m * N + n]);
    }
}

// ---------------------------------------------------------------------------
// MFMA bf16 flash attention.
// grid = (64, 12), block = 256 (4 waves). Wave w owns q rows [w*16, w*16+16).
// qkv is bf16 [T, 3C]; out is fp32 [T, C].
// MFMA 16x16x32 bf16 layouts (verified, guide §3):
//   A: m=lane&15, k=(lane>>4)*8+j     B: n=lane&15, k=(lane>>4)*8+j
//   C/D: col=lane&15, row=(lane>>4)*4+reg
// ---------------------------------------------------------------------------
#define QKV_STRIDE 80  // shorts per LDS row (160 B, 16B-aligned)
#define P_STRIDE   72  // shorts per LDS row (144 B, 16B-aligned)

__global__ __launch_bounds__(256) void flash_attn_mfma(
    const unsigned short* __restrict__ qkv, float* __restrict__ out) {
  __shared__ unsigned short Qs[64 * QKV_STRIDE];
  __shared__ unsigned short Ks[64 * QKV_STRIDE];
  __shared__ unsigned short Vt[64 * QKV_STRIDE];  // transposed: [d][key]
  __shared__ unsigned short Ps[64 * P_STRIDE];    // [q local][key]

  const int h = blockIdx.y;
  const int qt = 63 - blockIdx.x;  // longest-first for load balance
  const int q0 = qt * 64;
  const int tid = threadIdx.x;
  const int wave = tid >> 6;
  const int lane = tid & 63;
  const int lo = lane & 15;  // m / n / col index
  const int g = lane >> 4;   // k-group
  const float scale = 0.125f;

  // stage Q tile (64 rows x 64 d), coalesced 16B chunks
  for (int c = tid; c < 512; c += 256) {
    int r = c >> 3, ch = c & 7;
    uint4 v = *(const uint4*)(qkv + (size_t)(q0 + r) * C3 + h * HD + ch * 8);
    *(uint4*)(Qs + r * QKV_STRIDE + ch * 8) = v;
  }
  __syncthreads();

  // Q A-fragments, fixed across the whole kt loop
  bf16x8 qa0 = *(const bf16x8*)(Qs + (wave * 16 + lo) * QKV_STRIDE + g * 8);
  bf16x8 qa1 = *(const bf16x8*)(Qs + (wave * 16 + lo) * QKV_STRIDE + 32 + g * 8);

  float m_i[4], l_i[4];
  f32x4 o_acc[4];
#pragma unroll
  for (int r = 0; r < 4; ++r) { m_i[r] = -1e30f; l_i[r] = 0.f; }
#pragma unroll
  for (int dt = 0; dt < 4; ++dt) o_acc[dt] = (f32x4){0.f, 0.f, 0.f, 0.f};

  for (int kt = 0; kt <= qt; ++kt) {
    const int k0 = kt * 64;
    __syncthreads();  // previous iteration's Ks/Vt readers done
    // stage K (row-major) and V (transposed) tiles
    for (int c = tid; c < 512; c += 256) {
      int r = c >> 3, ch = c & 7;
      uint4 kv = *(const uint4*)(qkv + (size_t)(k0 + r) * C3 + C_DIM + h * HD + ch * 8);
      *(uint4*)(Ks + r * QKV_STRIDE + ch * 8) = kv;
      union { uint4 v; unsigned short u[8]; } vv;
      vv.v = *(const uint4*)(qkv + (size_t)(k0 + r) * C3 + 2 * C_DIM + h * HD + ch * 8);
#pragma unroll
      for (int j = 0; j < 8; ++j) Vt[(ch * 8 + j) * QKV_STRIDE + r] = vv.u[j];
    }
    __syncthreads();

    // S = Q @ K^T : wave computes 16 q-rows x 64 k-cols (4 n-tiles x 2 k-halves)
    f32x4 s[4];
#pragma unroll
    for (int nt = 0; nt < 4; ++nt) s[nt] = (f32x4){0.f, 0.f, 0.f, 0.f};
#pragma unroll
    for (int nt = 0; nt < 4; ++nt) {
      bf16x8 kb0 = *(const bf16x8*)(Ks + (nt * 16 + lo) * QKV_STRIDE + g * 8);
      bf16x8 kb1 = *(const bf16x8*)(Ks + (nt * 16 + lo) * QKV_STRIDE + 32 + g * 8);
      s[nt] = __builtin_amdgcn_mfma_f32_16x16x32_bf16(qa0, kb0, s[nt], 0, 0, 0);
      s[nt] = __builtin_amdgcn_mfma_f32_16x16x32_bf16(qa1, kb1, s[nt], 0, 0, 0);
    }

    // online softmax per owned row (row = wave*16 + g*4 + r locally)
    const bool diag = (kt == qt);
#pragma unroll
    for (int r = 0; r < 4; ++r) {
      float p[4];
      float mx = m_i[r];
#pragma unroll
      for (int nt = 0; nt < 4; ++nt) {
        float v = s[nt][r] * scale;
        if (diag && (nt * 16 + lo > wave * 16 + g * 4 + r)) v = -1e30f;
        p[nt] = v;
        mx = fmaxf(mx, v);
      }
#pragma unroll
      for (int off = 1; off < 16; off <<= 1) mx = fmaxf(mx, __shfl_xor(mx, off));
      const float alpha = __expf(m_i[r] - mx);
      m_i[r] = mx;
      float lsum = 0.f;
#pragma unroll
      for (int nt = 0; nt < 4; ++nt) {
        float e = __expf(p[nt] - mx);
        lsum += e;
        Ps[(wave * 16 + g * 4 + r) * P_STRIDE + nt * 16 + lo] = f2bf(e);
      }
#pragma unroll
      for (int off = 1; off < 16; off <<= 1) lsum += __shfl_xor(lsum, off);
      l_i[r] = l_i[r] * alpha + lsum;
#pragma unroll
      for (int dt = 0; dt < 4; ++dt) o_acc[dt][r] *= alpha;
    }
    // No barrier needed: each wave reads back only the Ps rows it wrote.

    // O += P @ V  (A from Ps, B from Vt — both contiguous bf16x8)
    bf16x8 pa0 = *(const bf16x8*)(Ps + (wave * 16 + lo) * P_STRIDE + g * 8);
    bf16x8 pa1 = *(const bf16x8*)(Ps + (wave * 16 + lo) * P_STRIDE + 32 + g * 8);
#pragma unroll
    for (int dt = 0; dt < 4; ++dt) {
      bf16x8 vb0 = *(const bf16x8*)(Vt + (dt * 16 + lo) * QKV_STRIDE + g * 8);
      bf16x8 vb1 = *(const bf16x8*)(Vt + (dt * 16 + lo) * QKV_STRIDE + 32 + g * 8);
      o_acc[dt] = __builtin_amdgcn_mfma_f32_16x16x32_bf16(pa0, vb0, o_acc[dt], 0, 0, 0);
      o_acc[dt] = __builtin_amdgcn_mfma_f32_16x16x32_bf16(pa1, vb1, o_acc[dt], 0, 0, 0);
    }
  }

  // epilogue: normalize and store fp32
#pragma unroll
  for (int r = 0; r < 4; ++r) {
    const float inv = 1.0f / l_i[r];
    const int row = q0 + wave * 16 + g * 4 + r;
#pragma unroll
    for (int dt = 0; dt < 4; ++dt)
      out[(size_t)row * C_DIM + h * HD + dt * 16 + lo] = o_acc[dt][r] * inv;
  }
}

// ---------------------------------------------------------------------------
extern "C" void kernel_launch(void* const* d_in, const int* in_sizes, int n_in,
                              void* d_out, int out_size, void* d_ws, size_t ws_size,
                              hipStream_t stream) {
  const float* x      = (const float*)d_in[0];
  const float* w_qkv  = (const float*)d_in[1];
  const float* b_qkv  = (const float*)d_in[2];
  const float* w_proj = (const float*)d_in[3];
  const float* b_proj = (const float*)d_in[4];
  float* out = (float*)d_out;

  unsigned short* qkv = (unsigned short*)d_ws;               // bf16 [4096,2304] 18.9 MB
  float* attn = (float*)(qkv + (size_t)T_SEQ * C3);          // fp32 [4096,768]  12.6 MB

  // qkv = bf16(x @ w_qkv + b_qkv)
  gemm_bias_f32_k<unsigned short><<<dim3(C3 / 64, T_SEQ / 64), 256, 0, stream>>>(
      x, w_qkv, b_qkv, qkv, T_SEQ, C3, C_DIM);

  // causal flash attention (MFMA bf16)
  flash_attn_mfma<<<dim3(T_SEQ / 64, NH), 256, 0, stream>>>(qkv, attn);

  // out = attn @ w_proj + b_proj
  gemm_bias_f32_k<float><<<dim3(C_DIM / 64, T_SEQ / 64), 256, 0, stream>>>(
      attn, w_proj, b_proj, out, T_SEQ, C_DIM, C_DIM);
}

// Round 3
// 367.313 us; speedup vs baseline: 3.6808x; 1.7435x over previous
//
#include <hip/hip_runtime.h>
#include <hip/hip_bf16.h>

// CausalSelfAttention  B=1, T=4096, C=768, H=12, hd=64
// Round 3: bf16 MFMA GEMMs (m97-style, global_load_lds) + MFMA flash attention.

#define T_SEQ 4096
#define C_DIM 768
#define C3    2304
#define NH    12
#define HD    64

typedef __attribute__((ext_vector_type(8))) short bf16x8;
typedef __attribute__((ext_vector_type(4))) float f32x4;

__device__ inline unsigned short f2bf(float f) {
  union { float f; unsigned u; } v; v.f = f;
  unsigned r = v.u + 0x7fff + ((v.u >> 16) & 1);  // RTNE
  return (unsigned short)(r >> 16);
}

__device__ inline void store_out(float v, float* p) { *p = v; }
__device__ inline void store_out(float v, unsigned short* p) { *p = f2bf(v); }

// async global->LDS, 16 bytes per lane. LDS dest semantics: wave-uniform base
// + lane*16 (m104/m108) — we pass base+lane*16 so either semantic is correct.
__device__ inline void gl2lds16(const void* g, void* l) {
  __builtin_amdgcn_global_load_lds(
      (const __attribute__((address_space(1))) unsigned int*)g,
      (__attribute__((address_space(3))) unsigned int*)l, 16, 0, 0);
}

// ---------------------------------------------------------------------------
// prep: fp32 -> bf16 elementwise (n divisible by 2048)
// ---------------------------------------------------------------------------
__global__ __launch_bounds__(256) void conv_f32_bf16(
    const float* __restrict__ in, unsigned short* __restrict__ out, int n) {
  int i = (blockIdx.x * 256 + threadIdx.x) * 8;
  if (i + 8 <= n) {
    float4 v0 = *(const float4*)(in + i);
    float4 v1 = *(const float4*)(in + i + 4);
    unsigned short o[8] = {f2bf(v0.x), f2bf(v0.y), f2bf(v0.z), f2bf(v0.w),
                           f2bf(v1.x), f2bf(v1.y), f2bf(v1.z), f2bf(v1.w)};
    *(uint4*)(out + i) = *(uint4*)o;
  }
}

// prep: transpose [R,Cc] fp32 -> [Cc,R] bf16 (R,Cc divisible by 32)
__global__ __launch_bounds__(256) void transpose_f32_bf16(
    const float* __restrict__ in, unsigned short* __restrict__ outT,
    int R, int Cc) {
  __shared__ float t[32][33];
  const int tx = threadIdx.x & 31, ty = threadIdx.x >> 5;
  const int c0 = blockIdx.x * 32, r0 = blockIdx.y * 32;
#pragma unroll
  for (int i = 0; i < 4; ++i) {
    int r = ty + i * 8;
    t[r][tx] = in[(size_t)(r0 + r) * Cc + c0 + tx];
  }
  __syncthreads();
#pragma unroll
  for (int i = 0; i < 4; ++i) {
    int c = ty + i * 8;
    outT[(size_t)(c0 + c) * R + r0 + tx] = f2bf(t[tx][c]);
  }
}

// ---------------------------------------------------------------------------
// bf16 MFMA GEMM, B-transposed input:  C[M,N] = A[M,K] @ Bt[N,K]^T + bias[N]
// 128x128 tile, BK=32, 256 threads (4 waves, 2x2 wave grid, 64x64 per wave).
// M,N divisible by 128; K divisible by 32.
// ---------------------------------------------------------------------------
template <typename OutT>
__global__ __launch_bounds__(256) void gemm_bt_mfma(
    const unsigned short* __restrict__ A, const unsigned short* __restrict__ Bt,
    const float* __restrict__ bias, OutT* __restrict__ C,
    int M, int N, int K) {
  __shared__ unsigned short As[128 * 32];  // [m][k], 64 B rows (no pad: lds-dma)
  __shared__ unsigned short Bs[128 * 32];  // [n][k]
  const int tid = threadIdx.x;
  const int wave = tid >> 6, lane = tid & 63;
  const int lo = lane & 15, g8 = lane >> 4;
  const int wm = wave >> 1, wn = wave & 1;
  const int bm = blockIdx.y * 128, bn = blockIdx.x * 128;
  const int lrow = lane >> 2;        // 0..15: row within 16-row chunk
  const int lcol = (lane & 3) * 8;   // 0/8/16/24: k-offset (shorts)

  f32x4 acc[4][4];
#pragma unroll
  for (int mt = 0; mt < 4; ++mt)
#pragma unroll
    for (int nt = 0; nt < 4; ++nt) acc[mt][nt] = (f32x4){0.f, 0.f, 0.f, 0.f};

  const unsigned short* Abase = A + (size_t)bm * K;
  const unsigned short* Bbase = Bt + (size_t)bn * K;

  for (int k0 = 0; k0 < K; k0 += 32) {
    __syncthreads();  // previous tile's readers done
#pragma unroll
    for (int c = 0; c < 2; ++c) {
      const int r = wave * 32 + c * 16;  // 16-row chunk staged per call
      gl2lds16(Abase + (size_t)(r + lrow) * K + k0 + lcol, As + r * 32 + lane * 8);
      gl2lds16(Bbase + (size_t)(r + lrow) * K + k0 + lcol, Bs + r * 32 + lane * 8);
    }
    __syncthreads();  // compiler emits vmcnt(0) drain before barrier

    bf16x8 a[4], b[4];
#pragma unroll
    for (int mt = 0; mt < 4; ++mt)
      a[mt] = *(const bf16x8*)(As + (wm * 64 + mt * 16 + lo) * 32 + g8 * 8);
#pragma unroll
    for (int nt = 0; nt < 4; ++nt)
      b[nt] = *(const bf16x8*)(Bs + (wn * 64 + nt * 16 + lo) * 32 + g8 * 8);
#pragma unroll
    for (int mt = 0; mt < 4; ++mt)
#pragma unroll
      for (int nt = 0; nt < 4; ++nt)
        acc[mt][nt] = __builtin_amdgcn_mfma_f32_16x16x32_bf16(a[mt], b[nt], acc[mt][nt], 0, 0, 0);
  }

  // epilogue: C/D layout col=lane&15, row=g8*4+r
#pragma unroll
  for (int nt = 0; nt < 4; ++nt) {
    const int n = bn + wn * 64 + nt * 16 + lo;
    const float bv = bias[n];
#pragma unroll
    for (int mt = 0; mt < 4; ++mt)
#pragma unroll
      for (int r = 0; r < 4; ++r) {
        const int m = bm + wm * 64 + mt * 16 + g8 * 4 + r;
        store_out(acc[mt][nt][r] + bv, &C[(size_t)m * N + n]);
      }
  }
}

// ---------------------------------------------------------------------------
// MFMA bf16 flash attention (unchanged from R2 except bf16 output).
// grid = (64, 12), block = 256 (4 waves). Wave w owns q rows [w*16, w*16+16).
// ---------------------------------------------------------------------------
#define QKV_STRIDE 80
#define P_STRIDE   72

__global__ __launch_bounds__(256) void flash_attn_mfma(
    const unsigned short* __restrict__ qkv, unsigned short* __restrict__ out) {
  __shared__ unsigned short Qs[64 * QKV_STRIDE];
  __shared__ unsigned short Ks[64 * QKV_STRIDE];
  __shared__ unsigned short Vt[64 * QKV_STRIDE];  // transposed: [d][key]
  __shared__ unsigned short Ps[64 * P_STRIDE];    // [q local][key]

  const int h = blockIdx.y;
  const int qt = 63 - blockIdx.x;  // longest-first
  const int q0 = qt * 64;
  const int tid = threadIdx.x;
  const int wave = tid >> 6;
  const int lane = tid & 63;
  const int lo = lane & 15;
  const int g = lane >> 4;
  const float scale = 0.125f;

  for (int c = tid; c < 512; c += 256) {
    int r = c >> 3, ch = c & 7;
    uint4 v = *(const uint4*)(qkv + (size_t)(q0 + r) * C3 + h * HD + ch * 8);
    *(uint4*)(Qs + r * QKV_STRIDE + ch * 8) = v;
  }
  __syncthreads();

  bf16x8 qa0 = *(const bf16x8*)(Qs + (wave * 16 + lo) * QKV_STRIDE + g * 8);
  bf16x8 qa1 = *(const bf16x8*)(Qs + (wave * 16 + lo) * QKV_STRIDE + 32 + g * 8);

  float m_i[4], l_i[4];
  f32x4 o_acc[4];
#pragma unroll
  for (int r = 0; r < 4; ++r) { m_i[r] = -1e30f; l_i[r] = 0.f; }
#pragma unroll
  for (int dt = 0; dt < 4; ++dt) o_acc[dt] = (f32x4){0.f, 0.f, 0.f, 0.f};

  for (int kt = 0; kt <= qt; ++kt) {
    const int k0 = kt * 64;
    __syncthreads();
    for (int c = tid; c < 512; c += 256) {
      int r = c >> 3, ch = c & 7;
      uint4 kv = *(const uint4*)(qkv + (size_t)(k0 + r) * C3 + C_DIM + h * HD + ch * 8);
      *(uint4*)(Ks + r * QKV_STRIDE + ch * 8) = kv;
      union { uint4 v; unsigned short u[8]; } vv;
      vv.v = *(const uint4*)(qkv + (size_t)(k0 + r) * C3 + 2 * C_DIM + h * HD + ch * 8);
#pragma unroll
      for (int j = 0; j < 8; ++j) Vt[(ch * 8 + j) * QKV_STRIDE + r] = vv.u[j];
    }
    __syncthreads();

    f32x4 s[4];
#pragma unroll
    for (int nt = 0; nt < 4; ++nt) s[nt] = (f32x4){0.f, 0.f, 0.f, 0.f};
#pragma unroll
    for (int nt = 0; nt < 4; ++nt) {
      bf16x8 kb0 = *(const bf16x8*)(Ks + (nt * 16 + lo) * QKV_STRIDE + g * 8);
      bf16x8 kb1 = *(const bf16x8*)(Ks + (nt * 16 + lo) * QKV_STRIDE + 32 + g * 8);
      s[nt] = __builtin_amdgcn_mfma_f32_16x16x32_bf16(qa0, kb0, s[nt], 0, 0, 0);
      s[nt] = __builtin_amdgcn_mfma_f32_16x16x32_bf16(qa1, kb1, s[nt], 0, 0, 0);
    }

    const bool diag = (kt == qt);
#pragma unroll
    for (int r = 0; r < 4; ++r) {
      float p[4];
      float mx = m_i[r];
#pragma unroll
      for (int nt = 0; nt < 4; ++nt) {
        float v = s[nt][r] * scale;
        if (diag && (nt * 16 + lo > wave * 16 + g * 4 + r)) v = -1e30f;
        p[nt] = v;
        mx = fmaxf(mx, v);
      }
#pragma unroll
      for (int off = 1; off < 16; off <<= 1) mx = fmaxf(mx, __shfl_xor(mx, off));
      const float alpha = __expf(m_i[r] - mx);
      m_i[r] = mx;
      float lsum = 0.f;
#pragma unroll
      for (int nt = 0; nt < 4; ++nt) {
        float e = __expf(p[nt] - mx);
        lsum += e;
        Ps[(wave * 16 + g * 4 + r) * P_STRIDE + nt * 16 + lo] = f2bf(e);
      }
#pragma unroll
      for (int off = 1; off < 16; off <<= 1) lsum += __shfl_xor(lsum, off);
      l_i[r] = l_i[r] * alpha + lsum;
#pragma unroll
      for (int dt = 0; dt < 4; ++dt) o_acc[dt][r] *= alpha;
    }

    bf16x8 pa0 = *(const bf16x8*)(Ps + (wave * 16 + lo) * P_STRIDE + g * 8);
    bf16x8 pa1 = *(const bf16x8*)(Ps + (wave * 16 + lo) * P_STRIDE + 32 + g * 8);
#pragma unroll
    for (int dt = 0; dt < 4; ++dt) {
      bf16x8 vb0 = *(const bf16x8*)(Vt + (dt * 16 + lo) * QKV_STRIDE + g * 8);
      bf16x8 vb1 = *(const bf16x8*)(Vt + (dt * 16 + lo) * QKV_STRIDE + 32 + g * 8);
      o_acc[dt] = __builtin_amdgcn_mfma_f32_16x16x32_bf16(pa0, vb0, o_acc[dt], 0, 0, 0);
      o_acc[dt] = __builtin_amdgcn_mfma_f32_16x16x32_bf16(pa1, vb1, o_acc[dt], 0, 0, 0);
    }
  }

#pragma unroll
  for (int r = 0; r < 4; ++r) {
    const float inv = 1.0f / l_i[r];
    const int row = q0 + wave * 16 + g * 4 + r;
#pragma unroll
    for (int dt = 0; dt < 4; ++dt)
      out[(size_t)row * C_DIM + h * HD + dt * 16 + lo] = f2bf(o_acc[dt][r] * inv);
  }
}

// ---------------------------------------------------------------------------
extern "C" void kernel_launch(void* const* d_in, const int* in_sizes, int n_in,
                              void* d_out, int out_size, void* d_ws, size_t ws_size,
                              hipStream_t stream) {
  const float* x      = (const float*)d_in[0];
  const float* w_qkv  = (const float*)d_in[1];
  const float* b_qkv  = (const float*)d_in[2];
  const float* w_proj = (const float*)d_in[3];
  const float* b_proj = (const float*)d_in[4];
  float* out = (float*)d_out;

  unsigned short* xb     = (unsigned short*)d_ws;               // [4096,768]
  unsigned short* wqkvT  = xb + (size_t)T_SEQ * C_DIM;          // [2304,768]
  unsigned short* wprojT = wqkvT + (size_t)C3 * C_DIM;          // [768,768]
  unsigned short* qkv    = wprojT + (size_t)C_DIM * C_DIM;      // [4096,2304]
  unsigned short* attnb  = qkv + (size_t)T_SEQ * C3;            // [4096,768]
  // total ~36 MB

  conv_f32_bf16<<<(T_SEQ * C_DIM) / 2048, 256, 0, stream>>>(x, xb, T_SEQ * C_DIM);
  transpose_f32_bf16<<<dim3(C3 / 32, C_DIM / 32), 256, 0, stream>>>(w_qkv, wqkvT, C_DIM, C3);
  transpose_f32_bf16<<<dim3(C_DIM / 32, C_DIM / 32), 256, 0, stream>>>(w_proj, wprojT, C_DIM, C_DIM);

  // qkv = bf16(xb @ wqkvT^T + b_qkv)
  gemm_bt_mfma<unsigned short><<<dim3(C3 / 128, T_SEQ / 128), 256, 0, stream>>>(
      xb, wqkvT, b_qkv, qkv, T_SEQ, C3, C_DIM);

  // causal flash attention (MFMA bf16) -> bf16
  flash_attn_mfma<<<dim3(T_SEQ / 64, NH), 256, 0, stream>>>(qkv, attnb);

  // out = attnb @ wprojT^T + b_proj (fp32 out)
  gemm_bt_mfma<float><<<dim3(C_DIM / 128, T_SEQ / 128), 256, 0, stream>>>(
      attnb, wprojT, b_proj, out, T_SEQ, C_DIM, C_DIM);
}

// Round 4
// 269.926 us; speedup vs baseline: 5.0088x; 1.3608x over previous
//
#include <hip/hip_runtime.h>
#include <hip/hip_bf16.h>

// CausalSelfAttention  B=1, T=4096, C=768, H=12, hd=64
// Round 4: flash kernel rework — global V^T, lds-dma staging, LPT order,
//          exp2 softmax, ones-MFMA row sums. GEMMs unchanged from R3.

#define T_SEQ 4096
#define C_DIM 768
#define C3    2304
#define NH    12
#define HD    64

typedef __attribute__((ext_vector_type(8))) short bf16x8;
typedef __attribute__((ext_vector_type(4))) float f32x4;

__device__ inline unsigned short f2bf(float f) {
  union { float f; unsigned u; } v; v.f = f;
  unsigned r = v.u + 0x7fff + ((v.u >> 16) & 1);  // RTNE
  return (unsigned short)(r >> 16);
}
__device__ inline float bf2f(unsigned short u) {
  union { unsigned u; float f; } v; v.u = (unsigned)u << 16;
  return v.f;
}

__device__ inline void store_out(float v, float* p) { *p = v; }
__device__ inline void store_out(float v, unsigned short* p) { *p = f2bf(v); }

__device__ inline void gl2lds16(const void* g, void* l) {
  __builtin_amdgcn_global_load_lds(
      (const __attribute__((address_space(1))) unsigned int*)g,
      (__attribute__((address_space(3))) unsigned int*)l, 16, 0, 0);
}

#if __has_builtin(__builtin_amdgcn_exp2f)
#define EXP2F(x) __builtin_amdgcn_exp2f(x)
#else
#define EXP2F(x) exp2f(x)
#endif

// ---------------------------------------------------------------------------
// prep: fp32 -> bf16 elementwise (n divisible by 2048)
// ---------------------------------------------------------------------------
__global__ __launch_bounds__(256) void conv_f32_bf16(
    const float* __restrict__ in, unsigned short* __restrict__ out, int n) {
  int i = (blockIdx.x * 256 + threadIdx.x) * 8;
  if (i + 8 <= n) {
    float4 v0 = *(const float4*)(in + i);
    float4 v1 = *(const float4*)(in + i + 4);
    unsigned short o[8] = {f2bf(v0.x), f2bf(v0.y), f2bf(v0.z), f2bf(v0.w),
                           f2bf(v1.x), f2bf(v1.y), f2bf(v1.z), f2bf(v1.w)};
    *(uint4*)(out + i) = *(uint4*)o;
  }
}

// prep: transpose [R,Cc] fp32 -> [Cc,R] bf16 (R,Cc divisible by 32)
__global__ __launch_bounds__(256) void transpose_f32_bf16(
    const float* __restrict__ in, unsigned short* __restrict__ outT,
    int R, int Cc) {
  __shared__ float t[32][33];
  const int tx = threadIdx.x & 31, ty = threadIdx.x >> 5;
  const int c0 = blockIdx.x * 32, r0 = blockIdx.y * 32;
#pragma unroll
  for (int i = 0; i < 4; ++i) {
    int r = ty + i * 8;
    t[r][tx] = in[(size_t)(r0 + r) * Cc + c0 + tx];
  }
  __syncthreads();
#pragma unroll
  for (int i = 0; i < 4; ++i) {
    int c = ty + i * 8;
    outT[(size_t)(c0 + c) * R + r0 + tx] = f2bf(t[tx][c]);
  }
}

// prep: V^T — read qkv V block [4096][768 of 2304], write vT[768][4096] bf16
__global__ __launch_bounds__(256) void transpose_v_bf16(
    const unsigned short* __restrict__ qkv, unsigned short* __restrict__ vT) {
  __shared__ unsigned short t[32][33];
  const int tx = threadIdx.x & 31, ty = threadIdx.x >> 5;
  const int c0 = blockIdx.x * 32;  // V column (0..767)
  const int r0 = blockIdx.y * 32;  // sequence row
#pragma unroll
  for (int i = 0; i < 4; ++i) {
    int r = ty + i * 8;
    t[r][tx] = qkv[(size_t)(r0 + r) * C3 + 2 * C_DIM + c0 + tx];
  }
  __syncthreads();
#pragma unroll
  for (int i = 0; i < 4; ++i) {
    int c = ty + i * 8;
    vT[(size_t)(c0 + c) * T_SEQ + r0 + tx] = t[tx][c];
  }
}

// ---------------------------------------------------------------------------
// bf16 MFMA GEMM, B-transposed input (unchanged from R3)
// ---------------------------------------------------------------------------
template <typename OutT>
__global__ __launch_bounds__(256) void gemm_bt_mfma(
    const unsigned short* __restrict__ A, const unsigned short* __restrict__ Bt,
    const float* __restrict__ bias, OutT* __restrict__ C,
    int M, int N, int K) {
  __shared__ unsigned short As[128 * 32];
  __shared__ unsigned short Bs[128 * 32];
  const int tid = threadIdx.x;
  const int wave = tid >> 6, lane = tid & 63;
  const int lo = lane & 15, g8 = lane >> 4;
  const int wm = wave >> 1, wn = wave & 1;
  const int bm = blockIdx.y * 128, bn = blockIdx.x * 128;
  const int lrow = lane >> 2;
  const int lcol = (lane & 3) * 8;

  f32x4 acc[4][4];
#pragma unroll
  for (int mt = 0; mt < 4; ++mt)
#pragma unroll
    for (int nt = 0; nt < 4; ++nt) acc[mt][nt] = (f32x4){0.f, 0.f, 0.f, 0.f};

  const unsigned short* Abase = A + (size_t)bm * K;
  const unsigned short* Bbase = Bt + (size_t)bn * K;

  for (int k0 = 0; k0 < K; k0 += 32) {
    __syncthreads();
#pragma unroll
    for (int c = 0; c < 2; ++c) {
      const int r = wave * 32 + c * 16;
      gl2lds16(Abase + (size_t)(r + lrow) * K + k0 + lcol, As + r * 32 + lane * 8);
      gl2lds16(Bbase + (size_t)(r + lrow) * K + k0 + lcol, Bs + r * 32 + lane * 8);
    }
    __syncthreads();

    bf16x8 a[4], b[4];
#pragma unroll
    for (int mt = 0; mt < 4; ++mt)
      a[mt] = *(const bf16x8*)(As + (wm * 64 + mt * 16 + lo) * 32 + g8 * 8);
#pragma unroll
    for (int nt = 0; nt < 4; ++nt)
      b[nt] = *(const bf16x8*)(Bs + (wn * 64 + nt * 16 + lo) * 32 + g8 * 8);
#pragma unroll
    for (int mt = 0; mt < 4; ++mt)
#pragma unroll
      for (int nt = 0; nt < 4; ++nt)
        acc[mt][nt] = __builtin_amdgcn_mfma_f32_16x16x32_bf16(a[mt], b[nt], acc[mt][nt], 0, 0, 0);
  }

#pragma unroll
  for (int nt = 0; nt < 4; ++nt) {
    const int n = bn + wn * 64 + nt * 16 + lo;
    const float bv = bias[n];
#pragma unroll
    for (int mt = 0; mt < 4; ++mt)
#pragma unroll
      for (int r = 0; r < 4; ++r) {
        const int m = bm + wm * 64 + mt * 16 + g8 * 4 + r;
        store_out(acc[mt][nt][r] + bv, &C[(size_t)m * N + n]);
      }
  }
}

// ---------------------------------------------------------------------------
// MFMA bf16 flash attention v2.
// 1-D grid 768 blocks, global LPT: qt = 63 - flat/12, h = flat%12.
// block = 256 (4 waves); wave w owns q rows [w*16, w*16+16).
// K/V tiles staged via global_load_lds into unpadded [64][64] LDS.
// Q pre-scaled by 0.125*log2e at staging (softmax in exp2 domain).
// Row sums l via ones-MFMA on P fragments.
// ---------------------------------------------------------------------------
#define Q_STRIDE 72
#define P_STRIDE 72

__global__ __launch_bounds__(256) void flash_attn_mfma2(
    const unsigned short* __restrict__ qkv,   // [T][2304] bf16
    const unsigned short* __restrict__ vT,    // [768][T] bf16
    unsigned short* __restrict__ out) {       // [T][768] bf16
  __shared__ unsigned short Qs[64 * Q_STRIDE];
  __shared__ unsigned short Ks[64 * 64];   // [key][d] — lds-dma, no pad
  __shared__ unsigned short Vs[64 * 64];   // [d][key] — lds-dma, no pad
  __shared__ unsigned short Ps[64 * P_STRIDE];

  const int flat = blockIdx.x;
  const int qt = 63 - flat / 12;   // global longest-first
  const int h = flat % 12;
  const int q0 = qt * 64;
  const int tid = threadIdx.x;
  const int wave = tid >> 6;
  const int lane = tid & 63;
  const int lo = lane & 15;
  const int g = lane >> 4;
  const float qscale = 0.125f * 1.44269504f;  // 1/sqrt(64) * log2(e)

  // stage Q (scaled), once per block
  for (int c = tid; c < 512; c += 256) {
    int r = c >> 3, ch = c & 7;
    union { uint4 v; unsigned short u[8]; } vv;
    vv.v = *(const uint4*)(qkv + (size_t)(q0 + r) * C3 + h * HD + ch * 8);
    unsigned short o[8];
#pragma unroll
    for (int j = 0; j < 8; ++j) o[j] = f2bf(bf2f(vv.u[j]) * qscale);
    *(uint4*)(Qs + r * Q_STRIDE + ch * 8) = *(uint4*)o;
  }
  __syncthreads();

  bf16x8 qa0 = *(const bf16x8*)(Qs + (wave * 16 + lo) * Q_STRIDE + g * 8);
  bf16x8 qa1 = *(const bf16x8*)(Qs + (wave * 16 + lo) * Q_STRIDE + 32 + g * 8);

  bf16x8 ones;
#pragma unroll
  for (int j = 0; j < 8; ++j) ones[j] = (short)0x3F80;  // bf16 1.0

  float m_i[4], l_i[4];
  f32x4 o_acc[4];
#pragma unroll
  for (int r = 0; r < 4; ++r) { m_i[r] = -1e30f; l_i[r] = 0.f; }
#pragma unroll
  for (int dt = 0; dt < 4; ++dt) o_acc[dt] = (f32x4){0.f, 0.f, 0.f, 0.f};

  const unsigned short* Kg = qkv + C_DIM + h * HD;          // row stride C3
  const unsigned short* Vg = vT + (size_t)(h * HD) * T_SEQ; // row stride T_SEQ
  const int sub = lane >> 3;        // 0..7 : row within 8-row dma chunk
  const int chk = (lane & 7) * 8;   // 0..56: short offset within 128B row

  for (int kt = 0; kt <= qt; ++kt) {
    const int k0 = kt * 64;
    __syncthreads();  // previous tile's readers done
    // each wave stages 16 rows of K and 16 d-rows of V^T (2 dma instrs each)
#pragma unroll
    for (int i = 0; i < 2; ++i) {
      const int r = wave * 16 + i * 8 + sub;
      gl2lds16(Kg + (size_t)(k0 + r) * C3 + chk, Ks + r * 64 + chk);
      gl2lds16(Vg + (size_t)r * T_SEQ + k0 + chk, Vs + r * 64 + chk);
    }
    __syncthreads();

    // S = Qhat @ K^T  (already in log2 domain)
    f32x4 s[4];
#pragma unroll
    for (int nt = 0; nt < 4; ++nt) s[nt] = (f32x4){0.f, 0.f, 0.f, 0.f};
#pragma unroll
    for (int nt = 0; nt < 4; ++nt) {
      bf16x8 kb0 = *(const bf16x8*)(Ks + (nt * 16 + lo) * 64 + g * 8);
      bf16x8 kb1 = *(const bf16x8*)(Ks + (nt * 16 + lo) * 64 + 32 + g * 8);
      s[nt] = __builtin_amdgcn_mfma_f32_16x16x32_bf16(qa0, kb0, s[nt], 0, 0, 0);
      s[nt] = __builtin_amdgcn_mfma_f32_16x16x32_bf16(qa1, kb1, s[nt], 0, 0, 0);
    }

    const bool diag = (kt == qt);
#pragma unroll
    for (int r = 0; r < 4; ++r) {
      float v[4];
      float mx = m_i[r];
#pragma unroll
      for (int nt = 0; nt < 4; ++nt) {
        float x = s[nt][r];
        if (diag && (nt * 16 + lo > wave * 16 + g * 4 + r)) x = -1e30f;
        v[nt] = x;
        mx = fmaxf(mx, x);
      }
#pragma unroll
      for (int off = 1; off < 16; off <<= 1) mx = fmaxf(mx, __shfl_xor(mx, off));
      const float alpha = EXP2F(m_i[r] - mx);
      m_i[r] = mx;
#pragma unroll
      for (int nt = 0; nt < 4; ++nt)
        Ps[(wave * 16 + g * 4 + r) * P_STRIDE + nt * 16 + lo] = f2bf(EXP2F(v[nt] - mx));
      l_i[r] *= alpha;
#pragma unroll
      for (int dt = 0; dt < 4; ++dt) o_acc[dt][r] *= alpha;
    }
    // each wave reads back only its own Ps rows — no barrier needed

    bf16x8 pa0 = *(const bf16x8*)(Ps + (wave * 16 + lo) * P_STRIDE + g * 8);
    bf16x8 pa1 = *(const bf16x8*)(Ps + (wave * 16 + lo) * P_STRIDE + 32 + g * 8);

    // row sums via ones-MFMA: D[q][*] = sum_k P[q][k]
    f32x4 lacc = (f32x4){0.f, 0.f, 0.f, 0.f};
    lacc = __builtin_amdgcn_mfma_f32_16x16x32_bf16(pa0, ones, lacc, 0, 0, 0);
    lacc = __builtin_amdgcn_mfma_f32_16x16x32_bf16(pa1, ones, lacc, 0, 0, 0);
#pragma unroll
    for (int r = 0; r < 4; ++r) l_i[r] += lacc[r];

    // O += P @ V
#pragma unroll
    for (int dt = 0; dt < 4; ++dt) {
      bf16x8 vb0 = *(const bf16x8*)(Vs + (dt * 16 + lo) * 64 + g * 8);
      bf16x8 vb1 = *(const bf16x8*)(Vs + (dt * 16 + lo) * 64 + 32 + g * 8);
      o_acc[dt] = __builtin_amdgcn_mfma_f32_16x16x32_bf16(pa0, vb0, o_acc[dt], 0, 0, 0);
      o_acc[dt] = __builtin_amdgcn_mfma_f32_16x16x32_bf16(pa1, vb1, o_acc[dt], 0, 0, 0);
    }
  }

#pragma unroll
  for (int r = 0; r < 4; ++r) {
    const float inv = 1.0f / l_i[r];
    const int row = q0 + wave * 16 + g * 4 + r;
#pragma unroll
    for (int dt = 0; dt < 4; ++dt)
      out[(size_t)row * C_DIM + h * HD + dt * 16 + lo] = f2bf(o_acc[dt][r] * inv);
  }
}

// ---------------------------------------------------------------------------
extern "C" void kernel_launch(void* const* d_in, const int* in_sizes, int n_in,
                              void* d_out, int out_size, void* d_ws, size_t ws_size,
                              hipStream_t stream) {
  const float* x      = (const float*)d_in[0];
  const float* w_qkv  = (const float*)d_in[1];
  const float* b_qkv  = (const float*)d_in[2];
  const float* w_proj = (const float*)d_in[3];
  const float* b_proj = (const float*)d_in[4];
  float* out = (float*)d_out;

  unsigned short* xb     = (unsigned short*)d_ws;               // [4096,768]
  unsigned short* wqkvT  = xb + (size_t)T_SEQ * C_DIM;          // [2304,768]
  unsigned short* wprojT = wqkvT + (size_t)C3 * C_DIM;          // [768,768]
  unsigned short* qkv    = wprojT + (size_t)C_DIM * C_DIM;      // [4096,2304]
  unsigned short* vT     = qkv + (size_t)T_SEQ * C3;            // [768,4096]
  unsigned short* attnb  = vT + (size_t)C_DIM * T_SEQ;          // [4096,768]
  // total ~42 MB

  conv_f32_bf16<<<(T_SEQ * C_DIM) / 2048, 256, 0, stream>>>(x, xb, T_SEQ * C_DIM);
  transpose_f32_bf16<<<dim3(C3 / 32, C_DIM / 32), 256, 0, stream>>>(w_qkv, wqkvT, C_DIM, C3);
  transpose_f32_bf16<<<dim3(C_DIM / 32, C_DIM / 32), 256, 0, stream>>>(w_proj, wprojT, C_DIM, C_DIM);

  gemm_bt_mfma<unsigned short><<<dim3(C3 / 128, T_SEQ / 128), 256, 0, stream>>>(
      xb, wqkvT, b_qkv, qkv, T_SEQ, C3, C_DIM);

  transpose_v_bf16<<<dim3(C_DIM / 32, T_SEQ / 32), 256, 0, stream>>>(qkv, vT);

  flash_attn_mfma2<<<dim3(T_SEQ / 64 * NH), 256, 0, stream>>>(qkv, vT, attnb);

  gemm_bt_mfma<float><<<dim3(C_DIM / 128, T_SEQ / 128), 256, 0, stream>>>(
      attnb, wprojT, b_proj, out, T_SEQ, C_DIM, C_DIM);
}

// Round 5
// 239.304 us; speedup vs baseline: 5.6497x; 1.1280x over previous
//
#include <hip/hip_runtime.h>
#include <hip/hip_bf16.h>

// CausalSelfAttention  B=1, T=4096, C=768, H=12, hd=64
// Round 5: flash v3 — XOR-swizzled K/V LDS (kills 8-way read conflicts),
//          double-buffered DMA staging, single barrier/iter.
//          GEMMs/preps unchanged from R4.

#define T_SEQ 4096
#define C_DIM 768
#define C3    2304
#define NH    12
#define HD    64

typedef __attribute__((ext_vector_type(8))) short bf16x8;
typedef __attribute__((ext_vector_type(4))) float f32x4;

__device__ inline unsigned short f2bf(float f) {
  union { float f; unsigned u; } v; v.f = f;
  unsigned r = v.u + 0x7fff + ((v.u >> 16) & 1);  // RTNE
  return (unsigned short)(r >> 16);
}
__device__ inline float bf2f(unsigned short u) {
  union { unsigned u; float f; } v; v.u = (unsigned)u << 16;
  return v.f;
}

__device__ inline void store_out(float v, float* p) { *p = v; }
__device__ inline void store_out(float v, unsigned short* p) { *p = f2bf(v); }

__device__ inline void gl2lds16(const void* g, void* l) {
  __builtin_amdgcn_global_load_lds(
      (const __attribute__((address_space(1))) unsigned int*)g,
      (__attribute__((address_space(3))) unsigned int*)l, 16, 0, 0);
}

#if __has_builtin(__builtin_amdgcn_exp2f)
#define EXP2F(x) __builtin_amdgcn_exp2f(x)
#else
#define EXP2F(x) exp2f(x)
#endif

// ---------------------------------------------------------------------------
// prep kernels (unchanged)
// ---------------------------------------------------------------------------
__global__ __launch_bounds__(256) void conv_f32_bf16(
    const float* __restrict__ in, unsigned short* __restrict__ out, int n) {
  int i = (blockIdx.x * 256 + threadIdx.x) * 8;
  if (i + 8 <= n) {
    float4 v0 = *(const float4*)(in + i);
    float4 v1 = *(const float4*)(in + i + 4);
    unsigned short o[8] = {f2bf(v0.x), f2bf(v0.y), f2bf(v0.z), f2bf(v0.w),
                           f2bf(v1.x), f2bf(v1.y), f2bf(v1.z), f2bf(v1.w)};
    *(uint4*)(out + i) = *(uint4*)o;
  }
}

__global__ __launch_bounds__(256) void transpose_f32_bf16(
    const float* __restrict__ in, unsigned short* __restrict__ outT,
    int R, int Cc) {
  __shared__ float t[32][33];
  const int tx = threadIdx.x & 31, ty = threadIdx.x >> 5;
  const int c0 = blockIdx.x * 32, r0 = blockIdx.y * 32;
#pragma unroll
  for (int i = 0; i < 4; ++i) {
    int r = ty + i * 8;
    t[r][tx] = in[(size_t)(r0 + r) * Cc + c0 + tx];
  }
  __syncthreads();
#pragma unroll
  for (int i = 0; i < 4; ++i) {
    int c = ty + i * 8;
    outT[(size_t)(c0 + c) * R + r0 + tx] = f2bf(t[tx][c]);
  }
}

__global__ __launch_bounds__(256) void transpose_v_bf16(
    const unsigned short* __restrict__ qkv, unsigned short* __restrict__ vT) {
  __shared__ unsigned short t[32][33];
  const int tx = threadIdx.x & 31, ty = threadIdx.x >> 5;
  const int c0 = blockIdx.x * 32;
  const int r0 = blockIdx.y * 32;
#pragma unroll
  for (int i = 0; i < 4; ++i) {
    int r = ty + i * 8;
    t[r][tx] = qkv[(size_t)(r0 + r) * C3 + 2 * C_DIM + c0 + tx];
  }
  __syncthreads();
#pragma unroll
  for (int i = 0; i < 4; ++i) {
    int c = ty + i * 8;
    vT[(size_t)(c0 + c) * T_SEQ + r0 + tx] = t[tx][c];
  }
}

// ---------------------------------------------------------------------------
// bf16 MFMA GEMM, B-transposed input (unchanged from R3/R4)
// ---------------------------------------------------------------------------
template <typename OutT>
__global__ __launch_bounds__(256) void gemm_bt_mfma(
    const unsigned short* __restrict__ A, const unsigned short* __restrict__ Bt,
    const float* __restrict__ bias, OutT* __restrict__ C,
    int M, int N, int K) {
  __shared__ unsigned short As[128 * 32];
  __shared__ unsigned short Bs[128 * 32];
  const int tid = threadIdx.x;
  const int wave = tid >> 6, lane = tid & 63;
  const int lo = lane & 15, g8 = lane >> 4;
  const int wm = wave >> 1, wn = wave & 1;
  const int bm = blockIdx.y * 128, bn = blockIdx.x * 128;
  const int lrow = lane >> 2;
  const int lcol = (lane & 3) * 8;

  f32x4 acc[4][4];
#pragma unroll
  for (int mt = 0; mt < 4; ++mt)
#pragma unroll
    for (int nt = 0; nt < 4; ++nt) acc[mt][nt] = (f32x4){0.f, 0.f, 0.f, 0.f};

  const unsigned short* Abase = A + (size_t)bm * K;
  const unsigned short* Bbase = Bt + (size_t)bn * K;

  for (int k0 = 0; k0 < K; k0 += 32) {
    __syncthreads();
#pragma unroll
    for (int c = 0; c < 2; ++c) {
      const int r = wave * 32 + c * 16;
      gl2lds16(Abase + (size_t)(r + lrow) * K + k0 + lcol, As + r * 32 + lane * 8);
      gl2lds16(Bbase + (size_t)(r + lrow) * K + k0 + lcol, Bs + r * 32 + lane * 8);
    }
    __syncthreads();

    bf16x8 a[4], b[4];
#pragma unroll
    for (int mt = 0; mt < 4; ++mt)
      a[mt] = *(const bf16x8*)(As + (wm * 64 + mt * 16 + lo) * 32 + g8 * 8);
#pragma unroll
    for (int nt = 0; nt < 4; ++nt)
      b[nt] = *(const bf16x8*)(Bs + (wn * 64 + nt * 16 + lo) * 32 + g8 * 8);
#pragma unroll
    for (int mt = 0; mt < 4; ++mt)
#pragma unroll
      for (int nt = 0; nt < 4; ++nt)
        acc[mt][nt] = __builtin_amdgcn_mfma_f32_16x16x32_bf16(a[mt], b[nt], acc[mt][nt], 0, 0, 0);
  }

#pragma unroll
  for (int nt = 0; nt < 4; ++nt) {
    const int n = bn + wn * 64 + nt * 16 + lo;
    const float bv = bias[n];
#pragma unroll
    for (int mt = 0; mt < 4; ++mt)
#pragma unroll
      for (int r = 0; r < 4; ++r) {
        const int m = bm + wm * 64 + mt * 16 + g8 * 4 + r;
        store_out(acc[mt][nt][r] + bv, &C[(size_t)m * N + n]);
      }
  }
}

// ---------------------------------------------------------------------------
// MFMA bf16 flash attention v3.
// XOR-swizzled K/V LDS: chunk c of row r stored at slot c^(r&7).
//   - DMA dest stays base+lane*16 (slot = lane&7, row's sub = lane>>3,
//     so source chunk = (lane&7) ^ (lane>>3)).
//   - fragment read slot = (g + half*4) ^ (lo&7): quarter-wave spreads over
//     all 8 slot groups -> 2-way only (free).
// Double-buffered K/V: one barrier per kt iteration; next tile's DMA issued
// immediately after the barrier, flying under compute.
// ---------------------------------------------------------------------------
#define Q_STRIDE 72
#define P_STRIDE 72

__global__ __launch_bounds__(256) void flash_attn_mfma3(
    const unsigned short* __restrict__ qkv,   // [T][2304] bf16
    const unsigned short* __restrict__ vT,    // [768][T] bf16
    unsigned short* __restrict__ out) {       // [T][768] bf16
  __shared__ unsigned short Qs[64 * Q_STRIDE];
  __shared__ unsigned short Ks[2][64 * 64];   // [key][slot^] swizzled
  __shared__ unsigned short Vs[2][64 * 64];   // [d][slot^]   swizzled
  __shared__ unsigned short Ps[64 * P_STRIDE];

  const int flat = blockIdx.x;
  const int qt = 63 - flat / 12;   // global longest-first
  const int h = flat % 12;
  const int q0 = qt * 64;
  const int tid = threadIdx.x;
  const int wave = tid >> 6;
  const int lane = tid & 63;
  const int lo = lane & 15;
  const int g = lane >> 4;
  const float qscale = 0.125f * 1.44269504f;

  const unsigned short* Kg = qkv + C_DIM + h * HD;          // row stride C3
  const unsigned short* Vg = vT + (size_t)(h * HD) * T_SEQ; // row stride T_SEQ
  const int sub = lane >> 3;                  // row within 8-row dma chunk
  const int slot8 = (lane & 7) * 8;           // dest slot offset (shorts)
  const int csrc8 = ((lane & 7) ^ sub) * 8;   // swizzled source chunk offset

  // stage Q (scaled)
  for (int c = tid; c < 512; c += 256) {
    int r = c >> 3, ch = c & 7;
    union { uint4 v; unsigned short u[8]; } vv;
    vv.v = *(const uint4*)(qkv + (size_t)(q0 + r) * C3 + h * HD + ch * 8);
    unsigned short o[8];
#pragma unroll
    for (int j = 0; j < 8; ++j) o[j] = f2bf(bf2f(vv.u[j]) * qscale);
    *(uint4*)(Qs + r * Q_STRIDE + ch * 8) = *(uint4*)o;
  }

  // prefetch tile 0 into buffer 0
#pragma unroll
  for (int i = 0; i < 2; ++i) {
    const int rr = wave * 16 + i * 8 + sub;
    gl2lds16(Kg + (size_t)rr * C3 + csrc8, Ks[0] + rr * 64 + slot8);
    gl2lds16(Vg + (size_t)rr * T_SEQ + csrc8, Vs[0] + rr * 64 + slot8);
  }
  __syncthreads();

  bf16x8 qa0 = *(const bf16x8*)(Qs + (wave * 16 + lo) * Q_STRIDE + g * 8);
  bf16x8 qa1 = *(const bf16x8*)(Qs + (wave * 16 + lo) * Q_STRIDE + 32 + g * 8);

  bf16x8 ones;
#pragma unroll
  for (int j = 0; j < 8; ++j) ones[j] = (short)0x3F80;

  float m_i[4], l_i[4];
  f32x4 o_acc[4];
#pragma unroll
  for (int r = 0; r < 4; ++r) { m_i[r] = -1e30f; l_i[r] = 0.f; }
#pragma unroll
  for (int dt = 0; dt < 4; ++dt) o_acc[dt] = (f32x4){0.f, 0.f, 0.f, 0.f};

  // swizzled fragment slot offsets (shorts): half 0 -> chunk g, half 1 -> g+4
  const int sl0 = (g ^ (lo & 7)) * 8;
  const int sl1 = ((g + 4) ^ (lo & 7)) * 8;

  for (int kt = 0; kt <= qt; ++kt) {
    const int b = kt & 1;
    // issue next tile's DMA (flies under this tile's compute)
    if (kt < qt) {
      const int k0n = (kt + 1) * 64;
#pragma unroll
      for (int i = 0; i < 2; ++i) {
        const int rr = wave * 16 + i * 8 + sub;
        gl2lds16(Kg + (size_t)(k0n + rr) * C3 + csrc8, Ks[b ^ 1] + rr * 64 + slot8);
        gl2lds16(Vg + (size_t)rr * T_SEQ + k0n + csrc8, Vs[b ^ 1] + rr * 64 + slot8);
      }
    }

    const unsigned short* Kb = Ks[b];
    const unsigned short* Vb = Vs[b];

    // S = Qhat @ K^T (log2 domain)
    f32x4 s[4];
#pragma unroll
    for (int nt = 0; nt < 4; ++nt) s[nt] = (f32x4){0.f, 0.f, 0.f, 0.f};
#pragma unroll
    for (int nt = 0; nt < 4; ++nt) {
      bf16x8 kb0 = *(const bf16x8*)(Kb + (nt * 16 + lo) * 64 + sl0);
      bf16x8 kb1 = *(const bf16x8*)(Kb + (nt * 16 + lo) * 64 + sl1);
      s[nt] = __builtin_amdgcn_mfma_f32_16x16x32_bf16(qa0, kb0, s[nt], 0, 0, 0);
      s[nt] = __builtin_amdgcn_mfma_f32_16x16x32_bf16(qa1, kb1, s[nt], 0, 0, 0);
    }

    const bool diag = (kt == qt);
#pragma unroll
    for (int r = 0; r < 4; ++r) {
      float v[4];
      float mx = m_i[r];
#pragma unroll
      for (int nt = 0; nt < 4; ++nt) {
        float x = s[nt][r];
        if (diag && (nt * 16 + lo > wave * 16 + g * 4 + r)) x = -1e30f;
        v[nt] = x;
        mx = fmaxf(mx, x);
      }
#pragma unroll
      for (int off = 1; off < 16; off <<= 1) mx = fmaxf(mx, __shfl_xor(mx, off));
      const float alpha = EXP2F(m_i[r] - mx);
      m_i[r] = mx;
#pragma unroll
      for (int nt = 0; nt < 4; ++nt)
        Ps[(wave * 16 + g * 4 + r) * P_STRIDE + nt * 16 + lo] = f2bf(EXP2F(v[nt] - mx));
      l_i[r] *= alpha;
#pragma unroll
      for (int dt = 0; dt < 4; ++dt) o_acc[dt][r] *= alpha;
    }
    // each wave reads back only its own Ps rows — no barrier needed

    bf16x8 pa0 = *(const bf16x8*)(Ps + (wave * 16 + lo) * P_STRIDE + g * 8);
    bf16x8 pa1 = *(const bf16x8*)(Ps + (wave * 16 + lo) * P_STRIDE + 32 + g * 8);

    f32x4 lacc = (f32x4){0.f, 0.f, 0.f, 0.f};
    lacc = __builtin_amdgcn_mfma_f32_16x16x32_bf16(pa0, ones, lacc, 0, 0, 0);
    lacc = __builtin_amdgcn_mfma_f32_16x16x32_bf16(pa1, ones, lacc, 0, 0, 0);
#pragma unroll
    for (int r = 0; r < 4; ++r) l_i[r] += lacc[r];

#pragma unroll
    for (int dt = 0; dt < 4; ++dt) {
      bf16x8 vb0 = *(const bf16x8*)(Vb + (dt * 16 + lo) * 64 + sl0);
      bf16x8 vb1 = *(const bf16x8*)(Vb + (dt * 16 + lo) * 64 + sl1);
      o_acc[dt] = __builtin_amdgcn_mfma_f32_16x16x32_bf16(pa0, vb0, o_acc[dt], 0, 0, 0);
      o_acc[dt] = __builtin_amdgcn_mfma_f32_16x16x32_bf16(pa1, vb1, o_acc[dt], 0, 0, 0);
    }

    // one barrier per iter: next buffer's DMA drained (compiler vmcnt(0)),
    // and all waves done reading buffer b before it's overwritten next iter.
    __syncthreads();
  }

#pragma unroll
  for (int r = 0; r < 4; ++r) {
    const float inv = 1.0f / l_i[r];
    const int row = q0 + wave * 16 + g * 4 + r;
#pragma unroll
    for (int dt = 0; dt < 4; ++dt)
      out[(size_t)row * C_DIM + h * HD + dt * 16 + lo] = f2bf(o_acc[dt][r] * inv);
  }
}

// ---------------------------------------------------------------------------
extern "C" void kernel_launch(void* const* d_in, const int* in_sizes, int n_in,
                              void* d_out, int out_size, void* d_ws, size_t ws_size,
                              hipStream_t stream) {
  const float* x      = (const float*)d_in[0];
  const float* w_qkv  = (const float*)d_in[1];
  const float* b_qkv  = (const float*)d_in[2];
  const float* w_proj = (const float*)d_in[3];
  const float* b_proj = (const float*)d_in[4];
  float* out = (float*)d_out;

  unsigned short* xb     = (unsigned short*)d_ws;               // [4096,768]
  unsigned short* wqkvT  = xb + (size_t)T_SEQ * C_DIM;          // [2304,768]
  unsigned short* wprojT = wqkvT + (size_t)C3 * C_DIM;          // [768,768]
  unsigned short* qkv    = wprojT + (size_t)C_DIM * C_DIM;      // [4096,2304]
  unsigned short* vT     = qkv + (size_t)T_SEQ * C3;            // [768,4096]
  unsigned short* attnb  = vT + (size_t)C_DIM * T_SEQ;          // [4096,768]

  conv_f32_bf16<<<(T_SEQ * C_DIM) / 2048, 256, 0, stream>>>(x, xb, T_SEQ * C_DIM);
  transpose_f32_bf16<<<dim3(C3 / 32, C_DIM / 32), 256, 0, stream>>>(w_qkv, wqkvT, C_DIM, C3);
  transpose_f32_bf16<<<dim3(C_DIM / 32, C_DIM / 32), 256, 0, stream>>>(w_proj, wprojT, C_DIM, C_DIM);

  gemm_bt_mfma<unsigned short><<<dim3(C3 / 128, T_SEQ / 128), 256, 0, stream>>>(
      xb, wqkvT, b_qkv, qkv, T_SEQ, C3, C_DIM);

  transpose_v_bf16<<<dim3(C_DIM / 32, T_SEQ / 32), 256, 0, stream>>>(qkv, vT);

  flash_attn_mfma3<<<dim3(T_SEQ / 64 * NH), 256, 0, stream>>>(qkv, vT, attnb);

  gemm_bt_mfma<float><<<dim3(C_DIM / 128, T_SEQ / 128), 256, 0, stream>>>(
      attnb, wprojT, b_proj, out, T_SEQ, C_DIM, C_DIM);
}